// Round 2
// baseline (2140.858 us; speedup 1.0000x reference)
//
#include <hip/hip_runtime.h>
#include <cstdint>

#define NBOX 12288
#define NWORDS 192
#define POS_THRESH 0.15f
#define NMS_THRESH 0.7f

typedef unsigned long long u64;

// ---------------- Kernel 1: 3x3 conv 1024->512 + bias + ReLU ----------------
// grid 512: nb = bid&7 (N-slab of 64, XCD-local), y = bid>>3 (image row).
// Tile M=64 (one row, x=0..63) x N=64, BK=32, 256 threads, 4x4 micro-tile.
__global__ __launch_bounds__(256) void conv3x3_relu(
    const float* __restrict__ X, const float* __restrict__ Wc,
    const float* __restrict__ Bc, float* __restrict__ Y)
{
  __shared__ float As[32][64];
  __shared__ float Bs[32][64];
  const int bid = blockIdx.x;
  const int nb = bid & 7;
  const int y  = bid >> 3;
  const int t  = threadIdx.x;
  const int am  = t & 63, akq = t >> 6;      // A loader: position, k-quarter
  const int bk  = t >> 3, bn  = (t & 7) * 8; // B loader: k-row, n-segment
  const int tm  = t & 15, tn  = t >> 4;      // compute: 16x16 thread grid

  float acc[4][4];
  #pragma unroll
  for (int i = 0; i < 4; ++i)
    #pragma unroll
    for (int j = 0; j < 4; ++j) acc[i][j] = 0.f;

  for (int tap = 0; tap < 9; ++tap) {
    const int dy = tap / 3 - 1;
    const int dx = tap % 3 - 1;
    const int yy = y + dy;
    const int xx = am + dx;
    const bool aok = (yy >= 0) && (yy < 64) && (xx >= 0) && (xx < 64);
    const float* ap = X + ((yy * 64 + xx) * 1024 + akq * 8);
    const float* bp = Wc + ((tap * 1024 + bk) * 512 + nb * 64 + bn);
    for (int kb = 0; kb < 32; ++kb) {
      float4 a0 = {0.f,0.f,0.f,0.f}, a1 = {0.f,0.f,0.f,0.f};
      if (aok) {
        a0 = *(const float4*)(ap);
        a1 = *(const float4*)(ap + 4);
      }
      const float4 b0 = *(const float4*)(bp);
      const float4 b1 = *(const float4*)(bp + 4);
      __syncthreads();  // previous iteration's readers done
      const int k0 = akq * 8;
      As[k0+0][am] = a0.x; As[k0+1][am] = a0.y; As[k0+2][am] = a0.z; As[k0+3][am] = a0.w;
      As[k0+4][am] = a1.x; As[k0+5][am] = a1.y; As[k0+6][am] = a1.z; As[k0+7][am] = a1.w;
      *(float4*)&Bs[bk][bn]     = b0;
      *(float4*)&Bs[bk][bn + 4] = b1;
      __syncthreads();
      #pragma unroll
      for (int k = 0; k < 32; ++k) {
        const float4 av = *(const float4*)&As[k][tm * 4];
        const float4 bv = *(const float4*)&Bs[k][tn * 4];
        const float af[4] = {av.x, av.y, av.z, av.w};
        const float bf[4] = {bv.x, bv.y, bv.z, bv.w};
        #pragma unroll
        for (int i = 0; i < 4; ++i)
          #pragma unroll
          for (int j = 0; j < 4; ++j)
            acc[i][j] = fmaf(af[i], bf[j], acc[i][j]);
      }
      ap += 32;        // next 32 channels
      bp += 32 * 512;  // next 32 k-rows
    }
  }

  const int n0 = nb * 64 + tn * 4;
  const float4 bias = *(const float4*)&Bc[n0];
  #pragma unroll
  for (int i = 0; i < 4; ++i) {
    const int m = tm * 4 + i;
    float4 v;
    v.x = fmaxf(acc[i][0] + bias.x, 0.f);
    v.y = fmaxf(acc[i][1] + bias.y, 0.f);
    v.z = fmaxf(acc[i][2] + bias.z, 0.f);
    v.w = fmaxf(acc[i][3] + bias.w, 0.f);
    *(float4*)&Y[(y * 64 + m) * 512 + n0] = v;
  }
}

// ---------------- Kernel 2: 1x1 heads + softmax(6) + decode ----------------
// grid 4096 (one block = one wave = one position).
__global__ __launch_bounds__(64) void heads_decode(
    const float* __restrict__ Yx, const float* __restrict__ Wcls,
    const float* __restrict__ bcls, const float* __restrict__ Wreg,
    const float* __restrict__ breg, float* __restrict__ boxes,
    float* __restrict__ scores)
{
  __shared__ float xs[512];
  const int pos = blockIdx.x;
  const int l = threadIdx.x;
  const float* xrow = Yx + (size_t)pos * 512;
  *(float4*)&xs[l * 8]     = *(const float4*)&xrow[l * 8];
  *(float4*)&xs[l * 8 + 4] = *(const float4*)&xrow[l * 8 + 4];
  __syncthreads();

  // lanes 0..5 -> cls logits, 6..17 -> reg outputs, others idle.
  const float* wp;
  int oc;
  float bini;
  if (l < 6)       { wp = Wcls + l;       oc = 6;  bini = bcls[l]; }
  else if (l < 18) { wp = Wreg + (l - 6); oc = 12; bini = breg[l - 6]; }
  else             { wp = Wcls;           oc = 0;  bini = 0.f; }
  float acc = bini;
  const float* p = wp;
  #pragma unroll 4
  for (int c = 0; c < 512; ++c) { acc = fmaf(xs[c], *p, acc); p += oc; }

  // gather 6 logits + 4 deltas for anchor a (lanes 0..2 write)
  const float l0 = __shfl(acc, 0), l1 = __shfl(acc, 1), l2 = __shfl(acc, 2);
  const float l3 = __shfl(acc, 3), l4 = __shfl(acc, 4), l5 = __shfl(acc, 5);
  const int a = (l < 3) ? l : 0;
  const float d0 = __shfl(acc, 6 + a * 4 + 0);
  const float d1 = __shfl(acc, 6 + a * 4 + 1);
  const float d2 = __shfl(acc, 6 + a * 4 + 2);
  const float d3 = __shfl(acc, 6 + a * 4 + 3);

  // softmax over all 6 channels (axis=-1), score = component 2a+1
  const float mx = fmaxf(fmaxf(fmaxf(l0, l1), fmaxf(l2, l3)), fmaxf(l4, l5));
  const float e0 = expf(l0 - mx), e1 = expf(l1 - mx), e2 = expf(l2 - mx);
  const float e3 = expf(l3 - mx), e4 = expf(l4 - mx), e5 = expf(l5 - mx);
  const float den = ((((e0 + e1) + e2) + e3) + e4) + e5;
  const float esel = (a == 0) ? e1 : ((a == 1) ? e3 : e5);
  const float sc = esel / den;

  // anchors (match np rounding)
  const int px = pos & 63, py = pos >> 6;
  const float cx = (px + 0.5f) * 16.0f;
  const float cy = (py + 0.5f) * 16.0f;
  const float ratio = (a == 0) ? 0.5f : ((a == 1) ? 1.0f : 2.0f);
  const float sq = sqrtf(ratio);
  const float wsz = 128.0f * sq;
  const float hsz = 128.0f / sq;
  const float a0 = cx - wsz * 0.5f;
  const float a1 = cy - hsz * 0.5f;
  const float a2 = cx + wsz * 0.5f;
  const float a3 = cy + hsz * 0.5f;
  const float w = a2 - a0, h = a3 - a1;
  const float xc = __fadd_rn(__fmul_rn(__fadd_rn(a0, a2), 0.5f), __fmul_rn(d0, w));
  const float yc = __fadd_rn(__fmul_rn(__fadd_rn(a1, a3), 0.5f), __fmul_rn(d1, h));
  const float nw = __fmul_rn(w, expf(d2));
  const float nh = __fmul_rn(h, expf(d3));
  float4 box;
  box.x = __fsub_rn(xc, __fmul_rn(nw, 0.5f));
  box.y = __fsub_rn(yc, __fmul_rn(nh, 0.5f));
  box.z = __fadd_rn(xc, __fmul_rn(nw, 0.5f));
  box.w = __fadd_rn(yc, __fmul_rn(nh, 0.5f));

  if (l < 3) {
    const int idx = pos * 3 + a;
    *(float4*)&boxes[idx * 4] = box;
    scores[idx] = sc;
  }
}

// ---------------- Kernel 3: suppression bit-matrix (ROW-major) + diagonal ----------------
// grid (192 words x 192 row-chunks); block 256 = 4 waves x 16 rows each.
// maskR[row * NWORDS + w] = 64 bits over columns j = w*64..w*64+63: IoU(row,j)>0.7 && j>row
// diagW[c*64 + r] = diagonal word (w == chunk of row) for fast phase-A loads.
__global__ __launch_bounds__(256) void build_mask(
    const float* __restrict__ boxes, u64* __restrict__ maskR,
    u64* __restrict__ diagW)
{
  const int w  = blockIdx.x;
  const int ci = blockIdx.y;
  if (w < ci) return;
  __shared__ float4 rb[64];
  const int t = threadIdx.x;
  const int lane = t & 63, wid = t >> 6;
  if (t < 64) rb[t] = *(const float4*)&boxes[(ci * 64 + t) * 4];
  const float4 cb = *(const float4*)&boxes[(w * 64 + lane) * 4];
  const float careaa = __fmul_rn(cb.z - cb.x, cb.w - cb.y);
  const int jglob = w * 64 + lane;
  __syncthreads();
  for (int rr = 0; rr < 16; ++rr) {
    const int r = wid * 16 + rr;
    const int row = ci * 64 + r;
    const float4 rx = rb[r];
    const float ra = __fmul_rn(rx.z - rx.x, rx.w - rx.y);
    const float xx1 = fmaxf(rx.x, cb.x);
    const float yy1 = fmaxf(rx.y, cb.y);
    const float xx2 = fminf(rx.z, cb.z);
    const float yy2 = fminf(rx.w, cb.w);
    const float iw = fmaxf(__fsub_rn(xx2, xx1), 0.f);
    const float ih = fmaxf(__fsub_rn(yy2, yy1), 0.f);
    const float inter = __fmul_rn(iw, ih);
    const float den = __fadd_rn(__fsub_rn(__fadd_rn(ra, careaa), inter), 1e-9f);
    const float iou = __fdiv_rn(inter, den);
    const bool bit = (iou > NMS_THRESH) && (jglob > row);
    const u64 word = __ballot(bit ? 1 : 0);
    if (lane == 0) {
      maskR[(size_t)row * NWORDS + w] = word;
      if (w == ci) diagW[ci * 64 + r] = word;
    }
  }
}

// ---------------- Kernel 4: sequential greedy NMS scan (single block) ----------------
// Insight: after the diagonal resolve of chunk c, alive[c] is FINAL (mask only
// has j > i bits). So phase B applies only finally-kept rows — a few hundred
// coalesced 8B*(191-c) row reads total instead of all 12288 rows.
__global__ __launch_bounds__(256) void nms_scan(
    const float* __restrict__ scores, const u64* __restrict__ maskR,
    const u64* __restrict__ diagW, u64* __restrict__ aliveOut)
{
  __shared__ u64 alive[NWORDS];
  const int t = threadIdx.x;
  if (t < NWORDS) {
    u64 wbits = 0ull;
    const float4* sp = (const float4*)(scores + t * 64);
    #pragma unroll
    for (int q = 0; q < 16; ++q) {
      const float4 s = sp[q];
      if (s.x > POS_THRESH) wbits |= (1ull << (q * 4 + 0));
      if (s.y > POS_THRESH) wbits |= (1ull << (q * 4 + 1));
      if (s.z > POS_THRESH) wbits |= (1ull << (q * 4 + 2));
      if (s.w > POS_THRESH) wbits |= (1ull << (q * 4 + 3));
    }
    alive[t] = wbits;
  }
  __syncthreads();
  const int lane = t & 63, wid = t >> 6;
  for (int c = 0; c < NWORDS; ++c) {
    if (alive[c] == 0ull) continue;   // uniform branch: nothing to resolve/apply
    // phase A: wave 0 resolves intra-chunk greedy suppression (set bits only)
    if (wid == 0) {
      const u64 dg = diagW[c * 64 + lane];   // contiguous 512B, L2-warm
      u64 aw = alive[c];
      u64 pending = aw;
      while (pending) {
        const int b = __ffsll((long long)pending) - 1;
        const u64 rbw = __shfl(dg, b);       // row b's intra-chunk suppression
        aw &= ~rbw;
        pending &= ~(rbw | (1ull << b));
      }
      if (lane == 0) alive[c] = aw;
    }
    __syncthreads();
    // phase B: finally-kept rows of chunk c suppress later words.
    // thread t owns word w=t; accumulate OR over kept rows, single AND.
    const u64 aw = alive[c];
    if (aw && t > c && t < NWORDS) {
      const u64* base = maskR + (size_t)(c * 64) * NWORDS + t;
      u64 sup = 0ull;
      u64 bits = aw;
      while (bits) {
        const int b = __ffsll((long long)bits) - 1;
        bits &= bits - 1;
        sup |= base[(size_t)b * NWORDS];     // coalesced across t
      }
      alive[t] &= ~sup;
    }
    __syncthreads();
  }
  if (t < NWORDS) aliveOut[t] = alive[t];
}

// ---------------- Kernel 5: masked output ----------------
__global__ __launch_bounds__(256) void write_output(
    const float* __restrict__ boxes, const u64* __restrict__ alive,
    float* __restrict__ out)
{
  const int i = blockIdx.x * 256 + threadIdx.x;
  if (i < NBOX) {
    const bool k = (alive[i >> 6] >> (i & 63)) & 1ull;
    const float4 b = *(const float4*)&boxes[i * 4];
    const float4 z = {0.f, 0.f, 0.f, 0.f};
    *(float4*)&out[i * 4] = k ? b : z;
  }
}

extern "C" void kernel_launch(void* const* d_in, const int* in_sizes, int n_in,
                              void* d_out, int out_size, void* d_ws, size_t ws_size,
                              hipStream_t stream) {
  const float* X    = (const float*)d_in[0];  // (1,64,64,1024)
  const float* Wc   = (const float*)d_in[1];  // (3,3,1024,512)
  const float* Bc   = (const float*)d_in[2];  // (512,)
  const float* Wcls = (const float*)d_in[3];  // (1,1,512,6)
  const float* bcls = (const float*)d_in[4];  // (6,)
  const float* Wreg = (const float*)d_in[5];  // (1,1,512,12)
  const float* breg = (const float*)d_in[6];  // (12,)

  char* ws = (char*)d_ws;
  float* Yx        = (float*)(ws);                 // 8,388,608 B
  float* boxes     = (float*)(ws + 8388608);       //   196,608 B
  float* scores    = (float*)(ws + 8585216);       //    49,152 B
  u64*   aliveG    = (u64*)  (ws + 8634368);       //     1,536 B
  u64*   diagW     = (u64*)  (ws + 8636416);       //    98,304 B
  u64*   maskR     = (u64*)  (ws + 8734720);       // 18,874,368 B (row-major)

  conv3x3_relu<<<512, 256, 0, stream>>>(X, Wc, Bc, Yx);
  heads_decode<<<4096, 64, 0, stream>>>(Yx, Wcls, bcls, Wreg, breg, boxes, scores);
  build_mask<<<dim3(192, 192), 256, 0, stream>>>(boxes, maskR, diagW);
  nms_scan<<<1, 256, 0, stream>>>(scores, maskR, diagW, aliveG);
  write_output<<<48, 256, 0, stream>>>(boxes, aliveG, (float*)d_out);
}

// Round 3
// 1391.166 us; speedup vs baseline: 1.5389x; 1.5389x over previous
//
#include <hip/hip_runtime.h>
#include <cstdint>

#define NBOX 12288
#define NWORDS 192
#define POS_THRESH 0.15f
#define NMS_THRESH 0.7f

typedef unsigned long long u64;

// ---------------- Kernel 1: 3x3 conv 1024->512 + bias + ReLU ----------------
// grid 512: nb = bid&7 (N-slab of 64, XCD-local), y = bid>>3 (image row).
// Tile M=64 (one row, x=0..63) x N=64, BK=32, 256 threads, 4x4 micro-tile.
__global__ __launch_bounds__(256) void conv3x3_relu(
    const float* __restrict__ X, const float* __restrict__ Wc,
    const float* __restrict__ Bc, float* __restrict__ Y)
{
  __shared__ float As[32][64];
  __shared__ float Bs[32][64];
  const int bid = blockIdx.x;
  const int nb = bid & 7;
  const int y  = bid >> 3;
  const int t  = threadIdx.x;
  const int am  = t & 63, akq = t >> 6;      // A loader: position, k-quarter
  const int bk  = t >> 3, bn  = (t & 7) * 8; // B loader: k-row, n-segment
  const int tm  = t & 15, tn  = t >> 4;      // compute: 16x16 thread grid

  float acc[4][4];
  #pragma unroll
  for (int i = 0; i < 4; ++i)
    #pragma unroll
    for (int j = 0; j < 4; ++j) acc[i][j] = 0.f;

  for (int tap = 0; tap < 9; ++tap) {
    const int dy = tap / 3 - 1;
    const int dx = tap % 3 - 1;
    const int yy = y + dy;
    const int xx = am + dx;
    const bool aok = (yy >= 0) && (yy < 64) && (xx >= 0) && (xx < 64);
    const float* ap = X + ((yy * 64 + xx) * 1024 + akq * 8);
    const float* bp = Wc + ((tap * 1024 + bk) * 512 + nb * 64 + bn);
    for (int kb = 0; kb < 32; ++kb) {
      float4 a0 = {0.f,0.f,0.f,0.f}, a1 = {0.f,0.f,0.f,0.f};
      if (aok) {
        a0 = *(const float4*)(ap);
        a1 = *(const float4*)(ap + 4);
      }
      const float4 b0 = *(const float4*)(bp);
      const float4 b1 = *(const float4*)(bp + 4);
      __syncthreads();  // previous iteration's readers done
      const int k0 = akq * 8;
      As[k0+0][am] = a0.x; As[k0+1][am] = a0.y; As[k0+2][am] = a0.z; As[k0+3][am] = a0.w;
      As[k0+4][am] = a1.x; As[k0+5][am] = a1.y; As[k0+6][am] = a1.z; As[k0+7][am] = a1.w;
      *(float4*)&Bs[bk][bn]     = b0;
      *(float4*)&Bs[bk][bn + 4] = b1;
      __syncthreads();
      #pragma unroll
      for (int k = 0; k < 32; ++k) {
        const float4 av = *(const float4*)&As[k][tm * 4];
        const float4 bv = *(const float4*)&Bs[k][tn * 4];
        const float af[4] = {av.x, av.y, av.z, av.w};
        const float bf[4] = {bv.x, bv.y, bv.z, bv.w};
        #pragma unroll
        for (int i = 0; i < 4; ++i)
          #pragma unroll
          for (int j = 0; j < 4; ++j)
            acc[i][j] = fmaf(af[i], bf[j], acc[i][j]);
      }
      ap += 32;        // next 32 channels
      bp += 32 * 512;  // next 32 k-rows
    }
  }

  const int n0 = nb * 64 + tn * 4;
  const float4 bias = *(const float4*)&Bc[n0];
  #pragma unroll
  for (int i = 0; i < 4; ++i) {
    const int m = tm * 4 + i;
    float4 v;
    v.x = fmaxf(acc[i][0] + bias.x, 0.f);
    v.y = fmaxf(acc[i][1] + bias.y, 0.f);
    v.z = fmaxf(acc[i][2] + bias.z, 0.f);
    v.w = fmaxf(acc[i][3] + bias.w, 0.f);
    *(float4*)&Y[(y * 64 + m) * 512 + n0] = v;
  }
}

// ---------------- Kernel 2: 1x1 heads + softmax(6) + decode + ext init ----------------
// grid 4096 (one block = one wave = one position).
__global__ __launch_bounds__(64) void heads_decode(
    const float* __restrict__ Yx, const float* __restrict__ Wcls,
    const float* __restrict__ bcls, const float* __restrict__ Wreg,
    const float* __restrict__ breg, float* __restrict__ boxes,
    float* __restrict__ scores, int* __restrict__ ext)
{
  __shared__ float xs[512];
  const int pos = blockIdx.x;
  const int l = threadIdx.x;
  if (l == 0 && pos < NWORDS) ext[pos] = pos;  // init extent array for build_mask
  const float* xrow = Yx + (size_t)pos * 512;
  *(float4*)&xs[l * 8]     = *(const float4*)&xrow[l * 8];
  *(float4*)&xs[l * 8 + 4] = *(const float4*)&xrow[l * 8 + 4];
  __syncthreads();

  // lanes 0..5 -> cls logits, 6..17 -> reg outputs, others idle.
  const float* wp;
  int oc;
  float bini;
  if (l < 6)       { wp = Wcls + l;       oc = 6;  bini = bcls[l]; }
  else if (l < 18) { wp = Wreg + (l - 6); oc = 12; bini = breg[l - 6]; }
  else             { wp = Wcls;           oc = 0;  bini = 0.f; }
  float acc = bini;
  const float* p = wp;
  #pragma unroll 4
  for (int c = 0; c < 512; ++c) { acc = fmaf(xs[c], *p, acc); p += oc; }

  // gather 6 logits + 4 deltas for anchor a (lanes 0..2 write)
  const float l0 = __shfl(acc, 0), l1 = __shfl(acc, 1), l2 = __shfl(acc, 2);
  const float l3 = __shfl(acc, 3), l4 = __shfl(acc, 4), l5 = __shfl(acc, 5);
  const int a = (l < 3) ? l : 0;
  const float d0 = __shfl(acc, 6 + a * 4 + 0);
  const float d1 = __shfl(acc, 6 + a * 4 + 1);
  const float d2 = __shfl(acc, 6 + a * 4 + 2);
  const float d3 = __shfl(acc, 6 + a * 4 + 3);

  // softmax over all 6 channels (axis=-1), score = component 2a+1
  const float mx = fmaxf(fmaxf(fmaxf(l0, l1), fmaxf(l2, l3)), fmaxf(l4, l5));
  const float e0 = expf(l0 - mx), e1 = expf(l1 - mx), e2 = expf(l2 - mx);
  const float e3 = expf(l3 - mx), e4 = expf(l4 - mx), e5 = expf(l5 - mx);
  const float den = ((((e0 + e1) + e2) + e3) + e4) + e5;
  const float esel = (a == 0) ? e1 : ((a == 1) ? e3 : e5);
  const float sc = esel / den;

  // anchors (match np rounding)
  const int px = pos & 63, py = pos >> 6;
  const float cx = (px + 0.5f) * 16.0f;
  const float cy = (py + 0.5f) * 16.0f;
  const float ratio = (a == 0) ? 0.5f : ((a == 1) ? 1.0f : 2.0f);
  const float sq = sqrtf(ratio);
  const float wsz = 128.0f * sq;
  const float hsz = 128.0f / sq;
  const float a0 = cx - wsz * 0.5f;
  const float a1 = cy - hsz * 0.5f;
  const float a2 = cx + wsz * 0.5f;
  const float a3 = cy + hsz * 0.5f;
  const float w = a2 - a0, h = a3 - a1;
  const float xc = __fadd_rn(__fmul_rn(__fadd_rn(a0, a2), 0.5f), __fmul_rn(d0, w));
  const float yc = __fadd_rn(__fmul_rn(__fadd_rn(a1, a3), 0.5f), __fmul_rn(d1, h));
  const float nw = __fmul_rn(w, expf(d2));
  const float nh = __fmul_rn(h, expf(d3));
  float4 box;
  box.x = __fsub_rn(xc, __fmul_rn(nw, 0.5f));
  box.y = __fsub_rn(yc, __fmul_rn(nh, 0.5f));
  box.z = __fadd_rn(xc, __fmul_rn(nw, 0.5f));
  box.w = __fadd_rn(yc, __fmul_rn(nh, 0.5f));

  if (l < 3) {
    const int idx = pos * 3 + a;
    *(float4*)&boxes[idx * 4] = box;
    scores[idx] = sc;
  }
}

// ---------------- Kernel 3: suppression bit-matrix (column-major) + extent ----------------
// grid (192 words x 192 row-chunks); block 256 = 4 waves x 16 rows each.
// maskT[w * NBOX + i] = 64 bits over columns j = w*64..w*64+63: IoU(i,j)>0.7 && j>i
// ext[ci] = max word index w with any set bit for rows of chunk ci (>= ci).
__global__ __launch_bounds__(256) void build_mask(
    const float* __restrict__ boxes, u64* __restrict__ maskT,
    int* __restrict__ ext)
{
  const int w  = blockIdx.x;
  const int ci = blockIdx.y;
  if (w < ci) return;
  __shared__ float4 rb[64];
  __shared__ int anyf;
  const int t = threadIdx.x;
  const int lane = t & 63, wid = t >> 6;
  if (t == 0) anyf = 0;
  if (t < 64) rb[t] = *(const float4*)&boxes[(ci * 64 + t) * 4];
  const float4 cb = *(const float4*)&boxes[(w * 64 + lane) * 4];
  const float careaa = __fmul_rn(cb.z - cb.x, cb.w - cb.y);
  const int jglob = w * 64 + lane;
  __syncthreads();
  bool any = false;
  for (int rr = 0; rr < 16; ++rr) {
    const int r = wid * 16 + rr;
    const int row = ci * 64 + r;
    const float4 rx = rb[r];
    const float ra = __fmul_rn(rx.z - rx.x, rx.w - rx.y);
    const float xx1 = fmaxf(rx.x, cb.x);
    const float yy1 = fmaxf(rx.y, cb.y);
    const float xx2 = fminf(rx.z, cb.z);
    const float yy2 = fminf(rx.w, cb.w);
    const float iw = fmaxf(__fsub_rn(xx2, xx1), 0.f);
    const float ih = fmaxf(__fsub_rn(yy2, yy1), 0.f);
    const float inter = __fmul_rn(iw, ih);
    const float den = __fadd_rn(__fsub_rn(__fadd_rn(ra, careaa), inter), 1e-9f);
    const float iou = __fdiv_rn(inter, den);
    const bool bit = (iou > NMS_THRESH) && (jglob > row);
    any |= bit;
    const u64 word = __ballot(bit ? 1 : 0);
    if (lane == 0) maskT[(size_t)w * NBOX + row] = word;
  }
  if (any) anyf = 1;     // benign race: all writers store 1
  __syncthreads();
  if (t == 0 && anyf && w > ci) atomicMax(&ext[ci], w);
}

// ---------------- Kernel 4: sequential greedy NMS scan (single block) ----------------
// Phase A resolves chunk c's greedy suppression (alive[c] final afterwards —
// mask bits require j>i). Phase B: branchless UNROLLED 64-row OR (loads
// pipeline; round-1-proven) limited to owner threads t in (c, ext[c]].
__global__ __launch_bounds__(256) void nms_scan(
    const float* __restrict__ scores, const u64* __restrict__ maskT,
    const int* __restrict__ ext, u64* __restrict__ aliveOut)
{
  __shared__ u64 alive[NWORDS];
  __shared__ int extS[NWORDS];
  const int t = threadIdx.x;
  if (t < NWORDS) {
    u64 wbits = 0ull;
    const float4* sp = (const float4*)(scores + t * 64);
    #pragma unroll
    for (int q = 0; q < 16; ++q) {
      const float4 s = sp[q];
      if (s.x > POS_THRESH) wbits |= (1ull << (q * 4 + 0));
      if (s.y > POS_THRESH) wbits |= (1ull << (q * 4 + 1));
      if (s.z > POS_THRESH) wbits |= (1ull << (q * 4 + 2));
      if (s.w > POS_THRESH) wbits |= (1ull << (q * 4 + 3));
    }
    alive[t] = wbits;
    extS[t] = ext[t];
  }
  __syncthreads();
  const int lane = t & 63, wid = t >> 6;
  for (int c = 0; c < NWORDS; ++c) {
    if (alive[c] == 0ull) continue;   // uniform: nothing to resolve/apply
    // phase A: wave 0 resolves intra-chunk greedy suppression (set bits only)
    if (wid == 0) {
      const u64 dg = maskT[(size_t)c * NBOX + c * 64 + lane];  // contiguous 512B
      u64 aw = alive[c];
      u64 pending = aw;
      while (pending) {
        const int b = __ffsll((long long)pending) - 1;
        const u64 rbw = __shfl(dg, b);       // row b's intra-chunk suppression
        aw &= ~rbw;
        pending &= ~(rbw | (1ull << b));
      }
      if (lane == 0) alive[c] = aw;
    }
    __syncthreads();
    // phase B: kept rows of chunk c suppress words (c, ext[c]] only.
    const u64 aw = alive[c];
    const int e = extS[c];
    if (aw && t > c && t <= e) {
      const u64* mp = maskT + (size_t)t * NBOX + c * 64;  // 512B contiguous
      u64 sup = 0ull;
      #pragma unroll
      for (int b = 0; b < 64; ++b) {
        const u64 m = mp[b];
        const u64 sel = 0ull - ((aw >> b) & 1ull);
        sup |= (m & sel);
      }
      alive[t] &= ~sup;
    }
    __syncthreads();
  }
  if (t < NWORDS) aliveOut[t] = alive[t];
}

// ---------------- Kernel 5: masked output ----------------
__global__ __launch_bounds__(256) void write_output(
    const float* __restrict__ boxes, const u64* __restrict__ alive,
    float* __restrict__ out)
{
  const int i = blockIdx.x * 256 + threadIdx.x;
  if (i < NBOX) {
    const bool k = (alive[i >> 6] >> (i & 63)) & 1ull;
    const float4 b = *(const float4*)&boxes[i * 4];
    const float4 z = {0.f, 0.f, 0.f, 0.f};
    *(float4*)&out[i * 4] = k ? b : z;
  }
}

extern "C" void kernel_launch(void* const* d_in, const int* in_sizes, int n_in,
                              void* d_out, int out_size, void* d_ws, size_t ws_size,
                              hipStream_t stream) {
  const float* X    = (const float*)d_in[0];  // (1,64,64,1024)
  const float* Wc   = (const float*)d_in[1];  // (3,3,1024,512)
  const float* Bc   = (const float*)d_in[2];  // (512,)
  const float* Wcls = (const float*)d_in[3];  // (1,1,512,6)
  const float* bcls = (const float*)d_in[4];  // (6,)
  const float* Wreg = (const float*)d_in[5];  // (1,1,512,12)
  const float* breg = (const float*)d_in[6];  // (12,)

  char* ws = (char*)d_ws;
  float* Yx        = (float*)(ws);                 // 8,388,608 B
  float* boxes     = (float*)(ws + 8388608);       //   196,608 B
  float* scores    = (float*)(ws + 8585216);       //    49,152 B
  u64*   aliveG    = (u64*)  (ws + 8634368);       //     1,536 B
  int*   extG      = (int*)  (ws + 8635904);       //       768 B
  u64*   maskT     = (u64*)  (ws + 8636672);       // 18,874,368 B (column-major)

  conv3x3_relu<<<512, 256, 0, stream>>>(X, Wc, Bc, Yx);
  heads_decode<<<4096, 64, 0, stream>>>(Yx, Wcls, bcls, Wreg, breg, boxes, scores, extG);
  build_mask<<<dim3(192, 192), 256, 0, stream>>>(boxes, maskT, extG);
  nms_scan<<<1, 256, 0, stream>>>(scores, maskT, extG, aliveG);
  write_output<<<48, 256, 0, stream>>>(boxes, aliveG, (float*)d_out);
}

// Round 4
// 1006.920 us; speedup vs baseline: 2.1261x; 1.3816x over previous
//
#include <hip/hip_runtime.h>
#include <cstdint>

#define NBOX 12288
#define NWORDS 192
#define POS_THRESH 0.15f
#define NMS_THRESH 0.7f

typedef unsigned long long u64;
typedef _Float16 half8 __attribute__((ext_vector_type(8)));
typedef float floatx4 __attribute__((ext_vector_type(4)));

// ---------------- Kernel 0a: zero the conv accumulator ----------------
__global__ __launch_bounds__(256) void zero_y(float4* __restrict__ Y) {
  Y[blockIdx.x * 256 + threadIdx.x] = float4{0.f, 0.f, 0.f, 0.f};
}

// ---------------- Kernel 0b: W (3,3,1024,512) -> WT[tap][n][c] fp16 h/l split ----------------
// l pre-scaled by 4096 so it stays in fp16 normal range (w~0.01 -> wl~2e-6 would be denormal).
__global__ __launch_bounds__(256) void prep_wt(
    const float* __restrict__ Wc, _Float16* __restrict__ WTh, _Float16* __restrict__ WTl)
{
  __shared__ float tile[64][65];
  const int b = blockIdx.x;           // 9 taps * 16 c-tiles * 8 n-tiles = 1152
  const int tap = b >> 7;
  const int rem = b & 127;
  const int c0 = (rem >> 3) * 64, n0 = (rem & 7) * 64;
  const int t = threadIdx.x;
  #pragma unroll
  for (int i = 0; i < 16; ++i) {
    const int idx = i * 256 + t;
    const int c = idx >> 6, n = idx & 63;
    tile[n][c] = Wc[((size_t)(tap * 1024 + c0 + c)) * 512 + n0 + n];
  }
  __syncthreads();
  #pragma unroll
  for (int i = 0; i < 16; ++i) {
    const int idx = i * 256 + t;
    const int n = idx >> 6, c = idx & 63;
    const float v = tile[n][c];
    const _Float16 h = (_Float16)v;
    const _Float16 l = (_Float16)((v - (float)h) * 4096.0f);
    const size_t o = ((size_t)(tap * 512 + n0 + n)) * 1024 + c0 + c;
    WTh[o] = h;
    WTl[o] = l;
  }
}

// ---------------- Kernel 1: 3x3 conv via split-fp16 MFMA ----------------
// grid 256: ks=bid&1 (K-slice of 512 ch), nt=(bid>>1)&3 (N-tile 128), mt=bid>>3 (2 image rows).
// bid&7 = (ks,nt) -> XCD-local 2.36MB weight slab. Tile 128x128, 4 waves of 64x64 (4x4 frags).
// A-halo (4 rows x 66 x, with h/l split computed in-kernel) staged once per K32-chunk,
// serves all 9 taps; B staged per (chunk,tap). atomicAdd epilogue (2 K-slices; commutative).
#define AROW 40                 // 32 k-halves padded to 40 (80B = 20 banks: 2-way only)
#define AS_PLANE (4 * 66 * AROW)
#define BS_PLANE (128 * AROW)
__global__ __launch_bounds__(256, 1) void conv_mfma(
    const float* __restrict__ X, const _Float16* __restrict__ WTh,
    const _Float16* __restrict__ WTl, float* __restrict__ Y)
{
  __shared__ _Float16 As[2 * AS_PLANE];   // 42,240 B
  __shared__ _Float16 Bs[2 * BS_PLANE];   // 20,480 B
  const int bid = blockIdx.x;
  const int ks = bid & 1;
  const int nt = (bid >> 1) & 3;
  const int mt = bid >> 3;
  const int t = threadIdx.x;
  const int lane = t & 63, wid = t >> 6;
  const int wm = wid >> 1, wn = wid & 1;
  const int lrow = lane & 15, quad = lane >> 4;

  floatx4 accH[4][4], accL[4][4];
  #pragma unroll
  for (int i = 0; i < 4; ++i)
    #pragma unroll
    for (int j = 0; j < 4; ++j) { accH[i][j] = (floatx4)0.f; accL[i][j] = (floatx4)0.f; }

  for (int kc = 0; kc < 16; ++kc) {
    const int c0 = ks * 512 + kc * 32;
    __syncthreads();   // prior chunk readers done
    // ---- stage A halo: 264 (yy,xx) rows x 32 ch, split to h/l ----
    for (int r = t; r < 264; r += 256) {
      const int yy = r / 66;
      const int xx = r - yy * 66;
      const int yi = mt * 2 + yy - 1;
      const int xi = xx - 1;
      _Float16* dsth = &As[(yy * 66 + xx) * AROW];
      _Float16* dstl = dsth + AS_PLANE;
      if (yi >= 0 && yi < 64 && xi >= 0 && xi < 64) {
        const float4* src = (const float4*)(X + ((size_t)(yi * 64 + xi)) * 1024 + c0);
        #pragma unroll
        for (int j = 0; j < 4; ++j) {
          const float4 va = src[2 * j], vb = src[2 * j + 1];
          const float f[8] = {va.x, va.y, va.z, va.w, vb.x, vb.y, vb.z, vb.w};
          half8 hh, hl;
          #pragma unroll
          for (int e = 0; e < 8; ++e) {
            const _Float16 h = (_Float16)f[e];
            hh[e] = h;
            hl[e] = (_Float16)((f[e] - (float)h) * 4096.0f);
          }
          *(half8*)&dsth[j * 8] = hh;
          *(half8*)&dstl[j * 8] = hl;
        }
      } else {
        const half8 z = (half8)(_Float16)0.f;
        #pragma unroll
        for (int j = 0; j < 4; ++j) { *(half8*)&dsth[j * 8] = z; *(half8*)&dstl[j * 8] = z; }
      }
    }
    for (int tap = 0; tap < 9; ++tap) {
      if (tap > 0) __syncthreads();   // prior tap's B readers done
      {   // ---- stage B: 256 rows (hl,n) x 32 halves ----
        const int hl = t >> 7, n = t & 127;
        const _Float16* src = (hl ? WTl : WTh) +
            ((size_t)(tap * 512 + nt * 128 + n)) * 1024 + c0;
        _Float16* dst = &Bs[hl * BS_PLANE + n * AROW];
        #pragma unroll
        for (int j = 0; j < 4; ++j)
          *(half8*)&dst[j * 8] = *(const half8*)&src[j * 8];
      }
      __syncthreads();   // A (first tap) + B visible
      const int dy = tap / 3 - 1, dx = tap - (tap / 3) * 3 - 1;
      const int yy = wm + dy + 1;
      const int xxb = dx + 1;
      half8 Ah[4], Al[4], Bh[4], Bl[4];
      #pragma unroll
      for (int fm = 0; fm < 4; ++fm) {
        const int idx = (yy * 66 + xxb + fm * 16 + lrow) * AROW + quad * 8;
        Ah[fm] = *(const half8*)&As[idx];
        Al[fm] = *(const half8*)&As[idx + AS_PLANE];
      }
      #pragma unroll
      for (int fn = 0; fn < 4; ++fn) {
        const int idx = (wn * 64 + fn * 16 + lrow) * AROW + quad * 8;
        Bh[fn] = *(const half8*)&Bs[idx];
        Bl[fn] = *(const half8*)&Bs[idx + BS_PLANE];
      }
      #pragma unroll
      for (int fm = 0; fm < 4; ++fm)
        #pragma unroll
        for (int fn = 0; fn < 4; ++fn) {
          accH[fm][fn] = __builtin_amdgcn_mfma_f32_16x16x32_f16(Ah[fm], Bh[fn], accH[fm][fn], 0, 0, 0);
          accL[fm][fn] = __builtin_amdgcn_mfma_f32_16x16x32_f16(Al[fm], Bh[fn], accL[fm][fn], 0, 0, 0);
          accL[fm][fn] = __builtin_amdgcn_mfma_f32_16x16x32_f16(Ah[fm], Bl[fn], accL[fm][fn], 0, 0, 0);
        }
    }
  }
  // ---- epilogue: combine scales, atomic-accumulate (2 K-slices per output) ----
  const int m0 = mt * 128 + wm * 64;
  const int n0 = nt * 128 + wn * 64;
  #pragma unroll
  for (int fm = 0; fm < 4; ++fm)
    #pragma unroll
    for (int fn = 0; fn < 4; ++fn) {
      const int n = n0 + fn * 16 + lrow;
      #pragma unroll
      for (int r = 0; r < 4; ++r) {
        const int m = m0 + fm * 16 + quad * 4 + r;
        atomicAdd(&Y[(size_t)m * 512 + n],
                  accH[fm][fn][r] + accL[fm][fn][r] * (1.0f / 4096.0f));
      }
    }
}

// ---------------- Kernel 2: bias+ReLU + 1x1 heads + softmax(6) + decode + ext init ----------------
__global__ __launch_bounds__(64) void heads_decode(
    const float* __restrict__ Yx, const float* __restrict__ Bc,
    const float* __restrict__ Wcls, const float* __restrict__ bcls,
    const float* __restrict__ Wreg, const float* __restrict__ breg,
    float* __restrict__ boxes, float* __restrict__ scores, int* __restrict__ ext)
{
  __shared__ float xs[512];
  const int pos = blockIdx.x;
  const int l = threadIdx.x;
  if (l == 0 && pos < NWORDS) ext[pos] = pos;
  const float* xrow = Yx + (size_t)pos * 512;
  float4 v0 = *(const float4*)&xrow[l * 8];
  float4 v1 = *(const float4*)&xrow[l * 8 + 4];
  const float4 b0 = *(const float4*)&Bc[l * 8];
  const float4 b1 = *(const float4*)&Bc[l * 8 + 4];
  xs[l * 8 + 0] = fmaxf(v0.x + b0.x, 0.f);
  xs[l * 8 + 1] = fmaxf(v0.y + b0.y, 0.f);
  xs[l * 8 + 2] = fmaxf(v0.z + b0.z, 0.f);
  xs[l * 8 + 3] = fmaxf(v0.w + b0.w, 0.f);
  xs[l * 8 + 4] = fmaxf(v1.x + b1.x, 0.f);
  xs[l * 8 + 5] = fmaxf(v1.y + b1.y, 0.f);
  xs[l * 8 + 6] = fmaxf(v1.z + b1.z, 0.f);
  xs[l * 8 + 7] = fmaxf(v1.w + b1.w, 0.f);
  __syncthreads();

  const float* wp;
  int oc;
  float bini;
  if (l < 6)       { wp = Wcls + l;       oc = 6;  bini = bcls[l]; }
  else if (l < 18) { wp = Wreg + (l - 6); oc = 12; bini = breg[l - 6]; }
  else             { wp = Wcls;           oc = 0;  bini = 0.f; }
  float acc = bini;
  const float* p = wp;
  #pragma unroll 4
  for (int c = 0; c < 512; ++c) { acc = fmaf(xs[c], *p, acc); p += oc; }

  const float l0 = __shfl(acc, 0), l1 = __shfl(acc, 1), l2 = __shfl(acc, 2);
  const float l3 = __shfl(acc, 3), l4 = __shfl(acc, 4), l5 = __shfl(acc, 5);
  const int a = (l < 3) ? l : 0;
  const float d0 = __shfl(acc, 6 + a * 4 + 0);
  const float d1 = __shfl(acc, 6 + a * 4 + 1);
  const float d2 = __shfl(acc, 6 + a * 4 + 2);
  const float d3 = __shfl(acc, 6 + a * 4 + 3);

  const float mx = fmaxf(fmaxf(fmaxf(l0, l1), fmaxf(l2, l3)), fmaxf(l4, l5));
  const float e0 = expf(l0 - mx), e1 = expf(l1 - mx), e2 = expf(l2 - mx);
  const float e3 = expf(l3 - mx), e4 = expf(l4 - mx), e5 = expf(l5 - mx);
  const float den = ((((e0 + e1) + e2) + e3) + e4) + e5;
  const float esel = (a == 0) ? e1 : ((a == 1) ? e3 : e5);
  const float sc = esel / den;

  const int px = pos & 63, py = pos >> 6;
  const float cx = (px + 0.5f) * 16.0f;
  const float cy = (py + 0.5f) * 16.0f;
  const float ratio = (a == 0) ? 0.5f : ((a == 1) ? 1.0f : 2.0f);
  const float sq = sqrtf(ratio);
  const float wsz = 128.0f * sq;
  const float hsz = 128.0f / sq;
  const float a0 = cx - wsz * 0.5f;
  const float a1 = cy - hsz * 0.5f;
  const float a2 = cx + wsz * 0.5f;
  const float a3 = cy + hsz * 0.5f;
  const float w = a2 - a0, h = a3 - a1;
  const float xc = __fadd_rn(__fmul_rn(__fadd_rn(a0, a2), 0.5f), __fmul_rn(d0, w));
  const float yc = __fadd_rn(__fmul_rn(__fadd_rn(a1, a3), 0.5f), __fmul_rn(d1, h));
  const float nw = __fmul_rn(w, expf(d2));
  const float nh = __fmul_rn(h, expf(d3));
  float4 box;
  box.x = __fsub_rn(xc, __fmul_rn(nw, 0.5f));
  box.y = __fsub_rn(yc, __fmul_rn(nh, 0.5f));
  box.z = __fadd_rn(xc, __fmul_rn(nw, 0.5f));
  box.w = __fadd_rn(yc, __fmul_rn(nh, 0.5f));

  if (l < 3) {
    const int idx = pos * 3 + a;
    *(float4*)&boxes[idx * 4] = box;
    scores[idx] = sc;
  }
}

// ---------------- Kernel 3: suppression bit-matrix (column-major) + extent ----------------
__global__ __launch_bounds__(256) void build_mask(
    const float* __restrict__ boxes, u64* __restrict__ maskT,
    int* __restrict__ ext)
{
  const int w  = blockIdx.x;
  const int ci = blockIdx.y;
  if (w < ci) return;
  __shared__ float4 rb[64];
  __shared__ int anyf;
  const int t = threadIdx.x;
  const int lane = t & 63, wid = t >> 6;
  if (t == 0) anyf = 0;
  if (t < 64) rb[t] = *(const float4*)&boxes[(ci * 64 + t) * 4];
  const float4 cb = *(const float4*)&boxes[(w * 64 + lane) * 4];
  const float careaa = __fmul_rn(cb.z - cb.x, cb.w - cb.y);
  const int jglob = w * 64 + lane;
  __syncthreads();
  bool any = false;
  for (int rr = 0; rr < 16; ++rr) {
    const int r = wid * 16 + rr;
    const int row = ci * 64 + r;
    const float4 rx = rb[r];
    const float ra = __fmul_rn(rx.z - rx.x, rx.w - rx.y);
    const float xx1 = fmaxf(rx.x, cb.x);
    const float yy1 = fmaxf(rx.y, cb.y);
    const float xx2 = fminf(rx.z, cb.z);
    const float yy2 = fminf(rx.w, cb.w);
    const float iw = fmaxf(__fsub_rn(xx2, xx1), 0.f);
    const float ih = fmaxf(__fsub_rn(yy2, yy1), 0.f);
    const float inter = __fmul_rn(iw, ih);
    const float den = __fadd_rn(__fsub_rn(__fadd_rn(ra, careaa), inter), 1e-9f);
    const float iou = __fdiv_rn(inter, den);
    const bool bit = (iou > NMS_THRESH) && (jglob > row);
    any |= bit;
    const u64 word = __ballot(bit ? 1 : 0);
    if (lane == 0) maskT[(size_t)w * NBOX + row] = word;
  }
  if (any) anyf = 1;
  __syncthreads();
  if (t == 0 && anyf && w > ci) atomicMax(&ext[ci], w);
}

// ---------------- Kernel 4: sequential greedy NMS scan (single block) ----------------
// v2: diag prefetch (wave1, latency hidden behind phase A+B) + kept-row list with
// groups-of-8 independent loads in phase B (one latency per 8 kept rows).
__global__ __launch_bounds__(256) void nms_scan(
    const float* __restrict__ scores, const u64* __restrict__ maskT,
    const int* __restrict__ ext, u64* __restrict__ aliveOut)
{
  __shared__ u64 alive[NWORDS];
  __shared__ int extS[NWORDS];
  __shared__ u64 dgbuf[2][64];
  __shared__ int rowsS[64];
  __shared__ int kcntS;
  const int t = threadIdx.x;
  const int lane = t & 63, wid = t >> 6;
  if (t < NWORDS) {
    u64 wbits = 0ull;
    const float4* sp = (const float4*)(scores + t * 64);
    #pragma unroll
    for (int q = 0; q < 16; ++q) {
      const float4 s = sp[q];
      if (s.x > POS_THRESH) wbits |= (1ull << (q * 4 + 0));
      if (s.y > POS_THRESH) wbits |= (1ull << (q * 4 + 1));
      if (s.z > POS_THRESH) wbits |= (1ull << (q * 4 + 2));
      if (s.w > POS_THRESH) wbits |= (1ull << (q * 4 + 3));
    }
    alive[t] = wbits;
    extS[t] = ext[t];
  }
  if (wid == 1) dgbuf[0][lane] = maskT[(size_t)0 * NBOX + lane];
  __syncthreads();
  for (int c = 0; c < NWORDS; ++c) {
    const u64 aw0 = alive[c];
    u64 pf = 0ull;
    if (wid == 1 && c + 1 < NWORDS)
      pf = maskT[(size_t)(c + 1) * NBOX + (c + 1) * 64 + lane];
    // phase A: wave 0 resolves intra-chunk greedy suppression from prefetched diag
    if (wid == 0) {
      if (aw0) {
        const u64 dg = dgbuf[c & 1][lane];
        u64 aw = aw0, pending = aw0;
        while (pending) {
          const int b = __ffsll((long long)pending) - 1;
          const u64 rbw = __shfl(dg, b);
          aw &= ~rbw;
          pending &= ~(rbw | (1ull << b));
        }
        const int my = __popcll(aw & ((1ull << lane) - 1ull));
        if ((aw >> lane) & 1ull) rowsS[my] = lane;
        if (lane == 0) { alive[c] = aw; kcntS = __popcll(aw); }
      } else if (lane == 0) {
        kcntS = 0;
      }
    }
    __syncthreads();
    // phase B: kept rows suppress words (c, ext[c]]; 8 independent loads per group
    const int kk = kcntS;
    const int e = extS[c];
    if (kk > 0 && t > c && t <= e) {
      const u64* colbase = maskT + (size_t)t * NBOX + c * 64;
      u64 sup = 0ull;
      for (int i = 0; i < kk; i += 8) {
        u64 m[8], sel[8];
        #pragma unroll
        for (int j = 0; j < 8; ++j) {
          const int ii = i + j;
          const int r = (ii < kk) ? rowsS[ii] : 0;
          m[j] = colbase[r];
          sel[j] = (ii < kk) ? ~0ull : 0ull;
        }
        #pragma unroll
        for (int j = 0; j < 8; ++j) sup |= (m[j] & sel[j]);
      }
      alive[t] &= ~sup;
    }
    if (wid == 1 && c + 1 < NWORDS) dgbuf[(c + 1) & 1][lane] = pf;
    __syncthreads();
  }
  if (t < NWORDS) aliveOut[t] = alive[t];
}

// ---------------- Kernel 5: masked output ----------------
__global__ __launch_bounds__(256) void write_output(
    const float* __restrict__ boxes, const u64* __restrict__ alive,
    float* __restrict__ out)
{
  const int i = blockIdx.x * 256 + threadIdx.x;
  if (i < NBOX) {
    const bool k = (alive[i >> 6] >> (i & 63)) & 1ull;
    const float4 b = *(const float4*)&boxes[i * 4];
    const float4 z = {0.f, 0.f, 0.f, 0.f};
    *(float4*)&out[i * 4] = k ? b : z;
  }
}

extern "C" void kernel_launch(void* const* d_in, const int* in_sizes, int n_in,
                              void* d_out, int out_size, void* d_ws, size_t ws_size,
                              hipStream_t stream) {
  const float* X    = (const float*)d_in[0];  // (1,64,64,1024)
  const float* Wc   = (const float*)d_in[1];  // (3,3,1024,512)
  const float* Bc   = (const float*)d_in[2];  // (512,)
  const float* Wcls = (const float*)d_in[3];  // (1,1,512,6)
  const float* bcls = (const float*)d_in[4];  // (6,)
  const float* Wreg = (const float*)d_in[5];  // (1,1,512,12)
  const float* breg = (const float*)d_in[6];  // (12,)

  char* ws = (char*)d_ws;
  float*     Y      = (float*)    (ws);                 // 8,388,608 B (raw conv sums)
  float*     boxes  = (float*)    (ws + 8388608);       //   196,608 B
  float*     scores = (float*)    (ws + 8585216);       //    49,152 B
  u64*       aliveG = (u64*)      (ws + 8634368);       //     1,536 B
  int*       extG   = (int*)      (ws + 8635904);       //       768 B
  // conv phase uses [8,636,672 .. 27,511,040) for WTh+WTl; maskT reuses the
  // SAME region after conv is done (both exactly 18,874,368 B).
  _Float16*  WTh    = (_Float16*) (ws + 8636672);       // 9,437,184 B
  _Float16*  WTl    = (_Float16*) (ws + 18073856);      // 9,437,184 B
  u64*       maskT  = (u64*)      (ws + 8636672);       // 18,874,368 B (post-conv)

  zero_y      <<<2048, 256, 0, stream>>>((float4*)Y);
  prep_wt     <<<1152, 256, 0, stream>>>(Wc, WTh, WTl);
  conv_mfma   <<<256, 256, 0, stream>>>(X, WTh, WTl, Y);
  heads_decode<<<4096, 64, 0, stream>>>(Y, Bc, Wcls, bcls, Wreg, breg, boxes, scores, extG);
  build_mask  <<<dim3(192, 192), 256, 0, stream>>>(boxes, maskT, extG);
  nms_scan    <<<1, 256, 0, stream>>>(scores, maskT, extG, aliveG);
  write_output<<<48, 256, 0, stream>>>(boxes, aliveG, (float*)d_out);
}